// Round 1
// baseline (184.173 us; speedup 1.0000x reference)
//
#include <hip/hip_runtime.h>
#include <hip/hip_bf16.h>
#include <stdint.h>

#define B_SZ   2048
#define DDATA  768
#define NSAE   128
#define NJK    4096   // NSAE*32
#define KA2    4352   // NJK + 128 (acts0) + 128 (gate)
#define SPLITK 4
#define KC2    1088   // KA2 / SPLITK (17 x BK=64)

typedef unsigned short u16;
typedef short bf16x8 __attribute__((ext_vector_type(8)));
typedef float f32x4  __attribute__((ext_vector_type(4)));

static __device__ __forceinline__ u16 f2bf(float f) {
  __hip_bfloat16 h = __float2bfloat16(f);
  return *reinterpret_cast<u16*>(&h);
}

static __device__ __forceinline__ void gload16(const u16* g, u16* l) {
  __builtin_amdgcn_global_load_lds(
      (const __attribute__((address_space(1))) unsigned int*)g,
      (__attribute__((address_space(3))) unsigned int*)l,
      16, 0, 0);
}

// ======== k_front: ALL pre-GEMM work in ONE kernel ========
// blocks   0..255 : gate/acts0 branch: 8 rows each; fp32 p=(x-bd0)@We0+be0,
//                   relu/gate -> A2, fused x->bf16 cast, fp64 fix-up in-wave.
//                   (wn computed in-register by wave 0 -> no cross-block dep)
// blocks 256..639 : expert j transpose We1[j]->W1T, dbk seg-split 3x (shorter
//                   latency chain); cv partials to cvp[seg] (summed in GEMM1)
// blocks 640..1455: B2T build ([W_dec1 ; W_dec0 ; b_dec1]^T), 68 rb x 12 dbk
__global__ __launch_bounds__(256) void k_front(const float* __restrict__ x,
                                               const float* __restrict__ We0,
                                               const float* __restrict__ be0,
                                               const float* __restrict__ bd0,
                                               const float* __restrict__ We1,
                                               const float* __restrict__ bd1,
                                               const float* __restrict__ be1,
                                               const float* __restrict__ Wd1,
                                               const float* __restrict__ Wd0,
                                               u16* __restrict__ W1T,
                                               float* __restrict__ cvp,
                                               u16* __restrict__ B2T,
                                               u16* __restrict__ xb,
                                               u16* __restrict__ A2) {
  __shared__ float smem[6280];                  // 25.1 KB, shared by all branches
  const int bid = blockIdx.x, t = threadIdx.x;
  if (bid < 256) {
    // ---------------- gate branch: rows b0..b0+7 ----------------
    const int b0 = bid * 8;
    float* xs  = smem;                          // [8][768] = x - bd0
    float* xns = smem + 6144;                   // [8]  ||x-bd0||^2
    float* wns = smem + 6152;                   // [128] ||We0[:,j]||
#pragma unroll
    for (int i = 0; i < 6; ++i) {
      int idx = t + i * 256;                    // 1536 float4
      int r = idx / 192, c4 = idx % 192;
      size_t go = (size_t)(b0 + r) * DDATA + c4 * 4;
      float4 v = *(const float4*)&x[go];
      ushort4 o;
      o.x = f2bf(v.x); o.y = f2bf(v.y); o.z = f2bf(v.z); o.w = f2bf(v.w);
      *(ushort4*)&xb[go] = o;                   // fused x cast for GEMM1
      float4 b4 = *(const float4*)&bd0[c4 * 4];
      v.x -= b4.x; v.y -= b4.y; v.z -= b4.z; v.w -= b4.w;
      *(float4*)&xs[r * DDATA + c4 * 4] = v;
    }
    __syncthreads();
    const int ln = t & 63, rg = t >> 6;         // wave rg owns rows rg*2, rg*2+1
    // row norms (stride-1 LDS, 2-way alias free; butterfly reduce)
#pragma unroll
    for (int rr = 0; rr < 2; ++rr) {
      int r = rg * 2 + rr;
      float a = 0.f;
#pragma unroll
      for (int q = 0; q < 12; ++q) { float xv = xs[r * DDATA + ln + q * 64]; a += xv * xv; }
#pragma unroll
      for (int sh = 32; sh; sh >>= 1) a += __shfl_xor(a, sh, 64);
      if (ln == 0) xns[r] = a;
    }
    const int j0 = ln * 2;                      // 2 experts per lane
    const float* xr0 = xs + (rg * 2) * DDATA;   // broadcast reads (wave-uniform addr)
    const float* xr1 = xr0 + DDATA;
    float pa0 = be0[j0], pa1 = be0[j0 + 1];
    float pb0 = pa0, pb1 = pa1;
    float wq0 = 0.f, wq1 = 0.f;
#define GBODY(WQ)                                                         \
    for (int d = 0; d < DDATA; d += 4) {                                  \
      _Pragma("unroll")                                                   \
      for (int dd = 0; dd < 4; ++dd) {                                    \
        float2 w2 = *(const float2*)&We0[(size_t)(d + dd) * 128 + j0];    \
        float a0 = xr0[d + dd], a1 = xr1[d + dd];                         \
        pa0 += a0 * w2.x; pa1 += a0 * w2.y;                               \
        pb0 += a1 * w2.x; pb1 += a1 * w2.y;                               \
        if (WQ) { wq0 += w2.x * w2.x; wq1 += w2.y * w2.y; }               \
      }                                                                   \
    }
    if (rg == 0) { GBODY(1); wns[j0] = sqrtf(wq0); wns[j0 + 1] = sqrtf(wq1); }
    else         { GBODY(0); }
#undef GBODY
    __syncthreads();
    const float sA = sqrtf(xns[rg * 2]), sB = sqrtf(xns[rg * 2 + 1]);
    const float w0 = wns[j0], w1 = wns[j0 + 1];
    const size_t rowA = (size_t)(b0 + rg * 2) * KA2;
    const size_t rowB = rowA + KA2;
    unsigned pka = (unsigned)f2bf(pa0 > 0.f ? pa0 : 0.f) |
                   ((unsigned)f2bf(pa1 > 0.f ? pa1 : 0.f) << 16);
    unsigned gka = (pa0 > 0.f ? 0x3F80u : 0u) | (pa1 > 0.f ? 0x3F800000u : 0u);
    unsigned pkb = (unsigned)f2bf(pb0 > 0.f ? pb0 : 0.f) |
                   ((unsigned)f2bf(pb1 > 0.f ? pb1 : 0.f) << 16);
    unsigned gkb = (pb0 > 0.f ? 0x3F80u : 0u) | (pb1 > 0.f ? 0x3F800000u : 0u);
    *(unsigned*)&A2[rowA + NJK + j0]       = pka;
    *(unsigned*)&A2[rowA + NJK + 128 + j0] = gka;
    *(unsigned*)&A2[rowB + NJK + j0]       = pkb;
    *(unsigned*)&A2[rowB + NJK + 128 + j0] = gkb;
    // fp32 sign uncertain -> whole wave cooperates on exact fp64 recompute
    const float tA0 = 1e-4f * sA * w0, tA1 = 1e-4f * sA * w1;
    const float tB0 = 1e-4f * sB * w0, tB1 = 1e-4f * sB * w1;
#pragma unroll
    for (int c = 0; c < 4; ++c) {
      float pv = c == 0 ? pa0 : c == 1 ? pa1 : c == 2 ? pb0 : pb1;
      float tv = c == 0 ? tA0 : c == 1 ? tA1 : c == 2 ? tB0 : tB1;
      unsigned long long mask = __ballot(fabsf(pv) <= tv);
      const int bb = b0 + rg * 2 + (c >> 1);
      while (mask) {
        int src = (int)__builtin_ctzll(mask);
        mask &= mask - 1;
        int jj = src * 2 + (c & 1);
        double acc = 0.0;
#pragma unroll
        for (int q = 0; q < 12; ++q) {
          int d = ln + q * 64;
          acc += (double)(x[(size_t)bb * DDATA + d] - bd0[d]) *
                 (double)We0[(size_t)d * 128 + jj];
        }
#pragma unroll
        for (int sh = 32; sh; sh >>= 1) acc += __shfl_xor(acc, sh, 64);
        if (ln == src) {
          double pd = acc + (double)be0[jj];
          size_t rw = (size_t)bb * KA2;
          A2[rw + NJK + jj]       = f2bf(pd > 0.0 ? (float)pd : 0.f);
          A2[rw + NJK + 128 + jj] = (pd > 0.0) ? (u16)0x3F80 : (u16)0;
        }
      }
    }
  } else if (bid < 640) {
    // ---------------- We1 transpose + cv partials (j, seg) ----------------
    const int e = bid - 256;
    const int j = e & 127, seg = e >> 7;        // seg 0..2 -> dbk seg*4..seg*4+3
    float* ts  = smem;                          // 64*33
    float* bds = smem + 64 * 33;                // 64
    float* red = smem + 64 * 33 + 64;           // 8*32
    const int k = t & 31, g = t >> 5;
    float cacc = 0.f;
    for (int db = seg * 4; db < seg * 4 + 4; ++db) {
      const float* src = We1 + (size_t)j * 24576 + db * 2048;  // 64 d x 32 k
#pragma unroll
      for (int i = 0; i < 8; ++i) {
        int ee = t + i * 256;
        ts[(ee >> 5) * 33 + (ee & 31)] = src[ee];
      }
      if (t < 64) bds[t] = bd1[(size_t)j * DDATA + db * 64 + t];
      __syncthreads();
#pragma unroll
      for (int i = 0; i < 8; ++i) {
        int ee = t + i * 256;
        int kk = ee >> 6, d = ee & 63;
        W1T[(size_t)(j * 32 + kk) * DDATA + db * 64 + d] = f2bf(ts[d * 33 + kk]);
      }
#pragma unroll
      for (int q = 0; q < 8; ++q) {
        int d = g + 8 * q;
        cacc += ts[d * 33 + k] * bds[d];
      }
      __syncthreads();
    }
    red[g * 32 + k] = cacc;
    __syncthreads();
    if (g == 0) {
      float s = 0.f;
#pragma unroll
      for (int q = 0; q < 8; ++q) s += red[q * 32 + k];
      cvp[seg * 4096 + j * 32 + k] = (seg == 0 ? be1[j * 32 + k] : 0.f) - s;
    }
  } else {
    // ---------------- B2T build ----------------
    const int e2 = bid - 640;
    const int rb = e2 / 12, dbk = e2 % 12;
    const float* src; int r0, base;
    if (rb < 64)      { src = Wd1; r0 = rb * 64;        base = 0;    }
    else if (rb < 66) { src = Wd0; r0 = (rb - 64) * 64; base = 4096; }
    else              { src = bd1; r0 = (rb - 66) * 64; base = 4224; }
    const int d0 = dbk * 64;
#pragma unroll
    for (int i = 0; i < 16; ++i) {
      int ee = t + i * 256;
      int ri = ee >> 6, di = ee & 63;
      smem[ri * 65 + di] = src[(size_t)(r0 + ri) * DDATA + d0 + di];
    }
    __syncthreads();
#pragma unroll
    for (int i = 0; i < 16; ++i) {
      int ee = t + i * 256;
      int di = ee >> 6, ri = ee & 63;
      B2T[(size_t)(d0 + di) * KA2 + base + r0 + ri] = f2bf(smem[ri * 65 + di]);
    }
  }
}

// ------ GEMM: C = A[M,K] * B^T[N,K], bf16 MFMA 16x16x32, BK=64, XOR-swizzled LDS ------
// 1-D grid + XCD-chunked decode: blocks sharing a B-panel land on ONE XCD, so
// the panel stays resident in that XCD's private 4MB L2 (T1 mechanism).
// EPI=1: grid 512 = 8 XCD-chunks of (4 bx x 16 by)  -> 3.9MB working set / XCD
// EPI=2: grid 768 = 8 XCD-chunks of 96, bx slowest  -> <=2 B-panels (2.2MB) / XCD
// EPI=1: v = relu(v + c[gn]) * gate -> bf16x2 A2 ;  EPI=2: split-K fp32 partials
template<int BM, int BN, int EPI>
__global__ __launch_bounds__(256) void k_gemm(const u16* __restrict__ A,
                                              const u16* __restrict__ Bm,
                                              int K, int Kc,
                                              float* __restrict__ outF,
                                              u16* __restrict__ A2,
                                              const float* __restrict__ cvec) {
  constexpr int WM = BM / 32, WN = BN / 32;
  __shared__ __align__(16) u16 As[BM * 64];
  __shared__ __align__(16) u16 Bs[BN * 64];
  __shared__ u16 gate_s[BM * 4];
  __shared__ float cv_s[BN];
  const int tid = threadIdx.x;
  int bx, by, bz;
  {
    const int h = blockIdx.x;
    if (EPI == 1) {
      const int l = (h & 7) * 64 + (h >> 3);    // bijective: 512 = 8*64
      const int g2 = l >> 6, w = l & 63;        // chunk g2 on XCD (h&7)
      by = w >> 2; bx = (g2 << 2) + (w & 3); bz = 0;
    } else {
      const int l = (h & 7) * 96 + (h >> 3);    // bijective: 768 = 8*96
      bx = l >> 7; const int r2 = l & 127; bz = r2 >> 5; by = r2 & 31;
    }
  }
  const int kbase = bz * Kc;
  const u16* Ab = A  + (size_t)(by * BM) * K;
  const u16* Bb = Bm + (size_t)(bx * BN) * K;
  const int wave = tid >> 6, lane = tid & 63;
  const int wr = wave >> 1, wc = wave & 1;
  const int m0 = wr * (BM / 2), n0 = wc * (BN / 2);
  const int lm = lane & 15, qd = lane >> 4;

  if (EPI == 1) {
    // preload epilogue data up front (ready; in-loop barriers cover the sync)
    for (int e = tid; e < BM * 4; e += 256) {
      int r = e >> 2, q = e & 3;
      gate_s[e] = A2[(size_t)(by * BM + r) * KA2 + NJK + 128 + bx * 4 + q];
    }
    for (int e = tid; e < BN; e += 256)
      cv_s[e] = cvec[bx * BN + e] + cvec[4096 + bx * BN + e] + cvec[8192 + bx * BN + e];
  }

  f32x4 acc[WM][WN];
  const f32x4 zero = {0.f, 0.f, 0.f, 0.f};
  for (int mi = 0; mi < WM; ++mi)
    for (int ni = 0; ni < WN; ++ni) acc[mi][ni] = zero;

  for (int k0 = kbase; k0 < kbase + Kc; k0 += 64) {
#pragma unroll
    for (int i = 0; i < BM / 32; ++i) {
      int id = tid + 256 * i;
      int row = id >> 3, u = id & 7;
      gload16(Ab + (size_t)row * K + k0 + ((u ^ (row & 7)) * 8), &As[id * 8]);
    }
#pragma unroll
    for (int i = 0; i < BN / 32; ++i) {
      int id = tid + 256 * i;
      int row = id >> 3, u = id & 7;
      gload16(Bb + (size_t)row * K + k0 + ((u ^ (row & 7)) * 8), &Bs[id * 8]);
    }
    __syncthreads();
#pragma unroll
    for (int s = 0; s < 2; ++s) {
      const int swz = ((s << 2) + qd) ^ (lm & 7);
      bf16x8 af[WM], bfv[WN];
#pragma unroll
      for (int mi = 0; mi < WM; ++mi)
        af[mi] = *(const bf16x8*)&As[(m0 + mi * 16 + lm) * 64 + swz * 8];
#pragma unroll
      for (int ni = 0; ni < WN; ++ni)
        bfv[ni] = *(const bf16x8*)&Bs[(n0 + ni * 16 + lm) * 64 + swz * 8];
#pragma unroll
      for (int mi = 0; mi < WM; ++mi)
#pragma unroll
        for (int ni = 0; ni < WN; ++ni)
          acc[mi][ni] = __builtin_amdgcn_mfma_f32_16x16x32_bf16(af[mi], bfv[ni],
                                                                acc[mi][ni], 0, 0, 0);
    }
    __syncthreads();
  }

  const int rb = qd * 4;
#pragma unroll
  for (int mi = 0; mi < WM; ++mi) {
#pragma unroll
    for (int ni = 0; ni < WN; ++ni) {
#pragma unroll
      for (int r = 0; r < 4; ++r) {
        int ml = m0 + mi * 16 + rb + r;
        int nl = n0 + ni * 16 + lm;
        int gm = by * BM + ml;
        int gn = bx * BN + nl;
        float v = acc[mi][ni][r];
        if (EPI == 1) {
          v += cv_s[nl];
          v = v > 0.f ? v : 0.f;
          u16 gbit = gate_s[ml * 4 + (nl >> 5)];
          v = gbit ? v : 0.f;
          float vn = __shfl_xor(v, 1, 64);        // pack even/odd columns
          if ((lm & 1) == 0) {
            unsigned pk = (unsigned)f2bf(v) | ((unsigned)f2bf(vn) << 16);
            *(unsigned*)&A2[(size_t)gm * KA2 + gn] = pk;
          }
        } else {
          outF[((size_t)bz * B_SZ + gm) * DDATA + gn] = v;
        }
      }
    }
  }
}

// ---------------- reduce split-K partials + bias ----------------
__global__ __launch_bounds__(256) void k_reduce(const float* __restrict__ part,
                                                const float* __restrict__ bias,
                                                float* __restrict__ out) {
  const int N4 = B_SZ * DDATA / 4;
  int i = blockIdx.x * 256 + threadIdx.x;
  const float4* p4 = (const float4*)part;
  float4 s = p4[i];
#pragma unroll
  for (int z = 1; z < SPLITK; ++z) {
    float4 t = p4[i + z * N4];
    s.x += t.x; s.y += t.y; s.z += t.z; s.w += t.w;
  }
  float4 b = ((const float4*)bias)[i % (DDATA / 4)];
  s.x += b.x; s.y += b.y; s.z += b.z; s.w += b.w;
  ((float4*)out)[i] = s;
}

extern "C" void kernel_launch(void* const* d_in, const int* in_sizes, int n_in,
                              void* d_out, int out_size, void* d_ws, size_t ws_size,
                              hipStream_t stream) {
  const float* x   = (const float*)d_in[0];
  const float* We0 = (const float*)d_in[1];
  const float* be0 = (const float*)d_in[2];
  const float* Wd0 = (const float*)d_in[3];
  const float* bd0 = (const float*)d_in[4];
  const float* We1 = (const float*)d_in[5];
  const float* be1 = (const float*)d_in[6];
  const float* Wd1 = (const float*)d_in[7];
  const float* bd1 = (const float*)d_in[8];
  float* out = (float*)d_out;

  uint8_t* ws = (uint8_t*)d_ws;
  size_t off = 0;
  auto carve = [&](size_t bytes) {
    uint8_t* p = ws + off;
    off += (bytes + 255) & ~(size_t)255;
    return p;
  };
  u16*    A2   = (u16*)carve((size_t)B_SZ * KA2 * 2);
  u16*    xb   = (u16*)carve((size_t)B_SZ * DDATA * 2);
  u16*    W1T  = (u16*)carve((size_t)NJK * DDATA * 2);
  u16*    B2T  = (u16*)carve((size_t)DDATA * KA2 * 2);
  float*  cvp  = (float*)carve((size_t)3 * NJK * 4);
  float*  part = (float*)carve((size_t)SPLITK * B_SZ * DDATA * 4);   // 25.2 MB

  // all pre-GEMM work (gate+acts0+fixup, W1T/cv, B2T, x-cast) in one kernel
  k_front <<<1456, 256, 0, stream>>>(x, We0, be0, bd0, We1, bd1, be1, Wd1, Wd0,
                                     W1T, cvp, B2T, xb, A2);
  // GEMM1: acts1 -> A2[:, 0..4095]   (M=2048, N=4096, K=768), XCD-chunked
  k_gemm<128, 128, 1><<<512, 256, 0, stream>>>(xb, W1T, DDATA, DDATA,
                                               nullptr, A2, cvp);
  // GEMM2 split-K: part[z] = A2 @ B2 over K-chunk z   (M=2048, N=768, K=4352)
  // BM=64, SPLITK=4 -> 768 blocks (3/CU); staging 535->321MB, B-panels L2-local
  k_gemm<64, 128, 2><<<768, 256, 0, stream>>>(A2, B2T, KA2, KC2,
                                              part, nullptr, nullptr);
  k_reduce<<<1536, 256, 0, stream>>>(part, bd0, out);
}

// Round 2
// 161.647 us; speedup vs baseline: 1.1394x; 1.1394x over previous
//
#include <hip/hip_runtime.h>
#include <hip/hip_bf16.h>
#include <stdint.h>

#define B_SZ   2048
#define DDATA  768
#define NSAE   128
#define NJK    4096   // NSAE*32
#define KA2    4352   // NJK + 128 (acts0) + 128 (gate)
#define SPLITK 4
#define KC2    1088   // KA2 / SPLITK (17 x BK=64)

typedef unsigned short u16;
typedef short bf16x8 __attribute__((ext_vector_type(8)));
typedef float f32x4  __attribute__((ext_vector_type(4)));

static __device__ __forceinline__ u16 f2bf(float f) {
  __hip_bfloat16 h = __float2bfloat16(f);
  return *reinterpret_cast<u16*>(&h);
}

static __device__ __forceinline__ void gload16(const u16* g, u16* l) {
  __builtin_amdgcn_global_load_lds(
      (const __attribute__((address_space(1))) unsigned int*)g,
      (__attribute__((address_space(3))) unsigned int*)l,
      16, 0, 0);
}

// ======== k_front: ALL pre-GEMM work in ONE kernel ========
// blocks    0..511 : gate/acts0: 4 rows/block, 4 waves split d into 192-chunks
//                    (short exposed load chains, 10 indep FMA chains/load),
//                    LDS cross-wave reduce, fused x->bf16 cast, fp64 fix-up.
// blocks  512..895 : expert j transpose We1[j]->W1T, dbk seg-split 3x;
//                    cv partials to cvp[seg] (summed in GEMM1 preload)
// blocks 896..1711 : B2T build ([W_dec1 ; W_dec0 ; b_dec1]^T), 68 rb x 12 dbk
__global__ __launch_bounds__(256) void k_front(const float* __restrict__ x,
                                               const float* __restrict__ We0,
                                               const float* __restrict__ be0,
                                               const float* __restrict__ bd0,
                                               const float* __restrict__ We1,
                                               const float* __restrict__ bd1,
                                               const float* __restrict__ be1,
                                               const float* __restrict__ Wd1,
                                               const float* __restrict__ Wd0,
                                               u16* __restrict__ W1T,
                                               float* __restrict__ cvp,
                                               u16* __restrict__ B2T,
                                               u16* __restrict__ xb,
                                               u16* __restrict__ A2) {
  __shared__ float smem[6280];                  // 25.1 KB, shared by all branches
  const int bid = blockIdx.x, t = threadIdx.x;
  if (bid < 512) {
    // ---------------- gate branch: rows b0..b0+3 ----------------
    const int b0 = bid * 4;
    float* xs   = smem;                         // [4][768] = x - bd0
    float* part = smem + 3072;                  // [4 waves][4 rows][128]
    float* wqp  = smem + 5120;                  // [4 waves][128] ||We0||^2 partials
    float* xns  = smem + 5632;                  // [4] row norms
#pragma unroll
    for (int i = 0; i < 3; ++i) {
      int idx = t + i * 256;                    // 768 float4
      int r = idx / 192, c4 = idx % 192;
      size_t go = (size_t)(b0 + r) * DDATA + c4 * 4;
      float4 v = *(const float4*)&x[go];
      ushort4 o;
      o.x = f2bf(v.x); o.y = f2bf(v.y); o.z = f2bf(v.z); o.w = f2bf(v.w);
      *(ushort4*)&xb[go] = o;                   // fused x cast for GEMM1
      float4 b4 = *(const float4*)&bd0[c4 * 4];
      v.x -= b4.x; v.y -= b4.y; v.z -= b4.z; v.w -= b4.w;
      *(float4*)&xs[r * DDATA + c4 * 4] = v;
    }
    __syncthreads();
    const int ln = t & 63, w = t >> 6;
    {                                           // row norm: wave w owns row w
      float a = 0.f;
#pragma unroll
      for (int q = 0; q < 12; ++q) { float xv = xs[w * DDATA + ln + q * 64]; a += xv * xv; }
#pragma unroll
      for (int sh = 32; sh; sh >>= 1) a += __shfl_xor(a, sh, 64);
      if (ln == 0) xns[w] = a;
    }
    const int j0 = ln * 2;                      // 2 experts per lane
    // wave w accumulates d in [w*192, w*192+192) for ALL 4 rows (partials)
    float a00=0.f,a01=0.f,a10=0.f,a11=0.f,a20=0.f,a21=0.f,a30=0.f,a31=0.f;
    float wq0=0.f, wq1=0.f;
    const int dbase = w * 192;
    for (int d = dbase; d < dbase + 192; d += 4) {
      float4 xv0 = *(const float4*)&xs[0 * DDATA + d];   // wave-uniform bcast
      float4 xv1 = *(const float4*)&xs[1 * DDATA + d];
      float4 xv2 = *(const float4*)&xs[2 * DDATA + d];
      float4 xv3 = *(const float4*)&xs[3 * DDATA + d];
#pragma unroll
      for (int dd = 0; dd < 4; ++dd) {
        float2 w2 = *(const float2*)&We0[(size_t)(d + dd) * 128 + j0];
        float x0 = ((const float*)&xv0)[dd], x1 = ((const float*)&xv1)[dd];
        float x2 = ((const float*)&xv2)[dd], x3 = ((const float*)&xv3)[dd];
        a00 += x0 * w2.x; a01 += x0 * w2.y;
        a10 += x1 * w2.x; a11 += x1 * w2.y;
        a20 += x2 * w2.x; a21 += x2 * w2.y;
        a30 += x3 * w2.x; a31 += x3 * w2.y;
        wq0 += w2.x * w2.x; wq1 += w2.y * w2.y;
      }
    }
    *(float2*)&part[(w * 4 + 0) * 128 + j0] = make_float2(a00, a01);
    *(float2*)&part[(w * 4 + 1) * 128 + j0] = make_float2(a10, a11);
    *(float2*)&part[(w * 4 + 2) * 128 + j0] = make_float2(a20, a21);
    *(float2*)&part[(w * 4 + 3) * 128 + j0] = make_float2(a30, a31);
    *(float2*)&wqp[w * 128 + j0] = make_float2(wq0, wq1);
    __syncthreads();
    // finalize: wave w owns row w; lane handles experts j0, j0+1
    float p0 = be0[j0], p1 = be0[j0 + 1];
    float wn0 = 0.f, wn1 = 0.f;
#pragma unroll
    for (int q = 0; q < 4; ++q) {
      float2 pr = *(const float2*)&part[(q * 4 + w) * 128 + j0];
      p0 += pr.x; p1 += pr.y;
      float2 wr2 = *(const float2*)&wqp[q * 128 + j0];
      wn0 += wr2.x; wn1 += wr2.y;
    }
    const float sx = sqrtf(xns[w]);
    const float tau0 = 1e-4f * sx * sqrtf(wn0);
    const float tau1 = 1e-4f * sx * sqrtf(wn1);
    const int bb = b0 + w;
    const size_t row = (size_t)bb * KA2;
    unsigned pk = (unsigned)f2bf(p0 > 0.f ? p0 : 0.f) |
                  ((unsigned)f2bf(p1 > 0.f ? p1 : 0.f) << 16);
    unsigned gk = (p0 > 0.f ? 0x3F80u : 0u) | (p1 > 0.f ? 0x3F800000u : 0u);
    *(unsigned*)&A2[row + NJK + j0]       = pk;
    *(unsigned*)&A2[row + NJK + 128 + j0] = gk;
    // fp32 sign uncertain -> whole wave cooperates on exact fp64 recompute
#pragma unroll
    for (int c = 0; c < 2; ++c) {
      float pv = c ? p1 : p0;
      float tv = c ? tau1 : tau0;
      unsigned long long mask = __ballot(fabsf(pv) <= tv);
      while (mask) {
        int src = (int)__builtin_ctzll(mask);
        mask &= mask - 1;
        int jj = src * 2 + c;
        double acc = 0.0;
#pragma unroll
        for (int q = 0; q < 12; ++q) {
          int d = ln + q * 64;
          acc += (double)(x[(size_t)bb * DDATA + d] - bd0[d]) *
                 (double)We0[(size_t)d * 128 + jj];
        }
#pragma unroll
        for (int sh = 32; sh; sh >>= 1) acc += __shfl_xor(acc, sh, 64);
        if (ln == src) {
          double pd = acc + (double)be0[jj];
          A2[row + NJK + jj]       = f2bf(pd > 0.0 ? (float)pd : 0.f);
          A2[row + NJK + 128 + jj] = (pd > 0.0) ? (u16)0x3F80 : (u16)0;
        }
      }
    }
  } else if (bid < 896) {
    // ---------------- We1 transpose + cv partials (j, seg) ----------------
    const int e = bid - 512;
    const int j = e & 127, seg = e >> 7;        // seg 0..2 -> dbk seg*4..seg*4+3
    float* ts  = smem;                          // 64*33
    float* bds = smem + 64 * 33;                // 64
    float* red = smem + 64 * 33 + 64;           // 8*32
    const int k = t & 31, g = t >> 5;
    float cacc = 0.f;
    for (int db = seg * 4; db < seg * 4 + 4; ++db) {
      const float* src = We1 + (size_t)j * 24576 + db * 2048;  // 64 d x 32 k
#pragma unroll
      for (int i = 0; i < 8; ++i) {
        int ee = t + i * 256;
        ts[(ee >> 5) * 33 + (ee & 31)] = src[ee];
      }
      if (t < 64) bds[t] = bd1[(size_t)j * DDATA + db * 64 + t];
      __syncthreads();
#pragma unroll
      for (int i = 0; i < 8; ++i) {
        int ee = t + i * 256;
        int kk = ee >> 6, d = ee & 63;
        W1T[(size_t)(j * 32 + kk) * DDATA + db * 64 + d] = f2bf(ts[d * 33 + kk]);
      }
#pragma unroll
      for (int q = 0; q < 8; ++q) {
        int d = g + 8 * q;
        cacc += ts[d * 33 + k] * bds[d];
      }
      __syncthreads();
    }
    red[g * 32 + k] = cacc;
    __syncthreads();
    if (g == 0) {
      float s = 0.f;
#pragma unroll
      for (int q = 0; q < 8; ++q) s += red[q * 32 + k];
      cvp[seg * 4096 + j * 32 + k] = (seg == 0 ? be1[j * 32 + k] : 0.f) - s;
    }
  } else {
    // ---------------- B2T build ----------------
    const int e2 = bid - 896;
    const int rb = e2 / 12, dbk = e2 % 12;
    const float* src; int r0, base;
    if (rb < 64)      { src = Wd1; r0 = rb * 64;        base = 0;    }
    else if (rb < 66) { src = Wd0; r0 = (rb - 64) * 64; base = 4096; }
    else              { src = bd1; r0 = (rb - 66) * 64; base = 4224; }
    const int d0 = dbk * 64;
#pragma unroll
    for (int i = 0; i < 16; ++i) {
      int ee = t + i * 256;
      int ri = ee >> 6, di = ee & 63;
      smem[ri * 65 + di] = src[(size_t)(r0 + ri) * DDATA + d0 + di];
    }
    __syncthreads();
#pragma unroll
    for (int i = 0; i < 16; ++i) {
      int ee = t + i * 256;
      int di = ee >> 6, ri = ee & 63;
      B2T[(size_t)(d0 + di) * KA2 + base + r0 + ri] = f2bf(smem[ri * 65 + di]);
    }
  }
}

// ------ GEMM: C = A[M,K] * B^T[N,K], bf16 MFMA 16x16x32, BK=64, XOR-swizzled LDS ------
// 1-D grid + XCD-chunked decode: blocks sharing a B-panel land on ONE XCD, so
// the panel stays resident in that XCD's private 4MB L2 (T1 mechanism).
// EPI=1: grid 512 = 8 XCD-chunks of (4 bx x 16 by)  -> 3.9MB working set / XCD
// EPI=2: grid 768 = 8 XCD-chunks of 96, bx slowest  -> <=2 B-panels (2.2MB) / XCD
// EPI=1: v = relu(v + c[gn]) * gate -> bf16x2 A2 ;  EPI=2: split-K fp32 partials
template<int BM, int BN, int EPI>
__global__ __launch_bounds__(256) void k_gemm(const u16* __restrict__ A,
                                              const u16* __restrict__ Bm,
                                              int K, int Kc,
                                              float* __restrict__ outF,
                                              u16* __restrict__ A2,
                                              const float* __restrict__ cvec) {
  constexpr int WM = BM / 32, WN = BN / 32;
  __shared__ __align__(16) u16 As[BM * 64];
  __shared__ __align__(16) u16 Bs[BN * 64];
  __shared__ u16 gate_s[BM * 4];
  __shared__ float cv_s[BN];
  const int tid = threadIdx.x;
  int bx, by, bz;
  {
    const int h = blockIdx.x;
    if (EPI == 1) {
      const int l = (h & 7) * 64 + (h >> 3);    // bijective: 512 = 8*64
      const int g2 = l >> 6, w = l & 63;        // chunk g2 on XCD (h&7)
      by = w >> 2; bx = (g2 << 2) + (w & 3); bz = 0;
    } else {
      const int l = (h & 7) * 96 + (h >> 3);    // bijective: 768 = 8*96
      bx = l >> 7; const int r2 = l & 127; bz = r2 >> 5; by = r2 & 31;
    }
  }
  const int kbase = bz * Kc;
  const u16* Ab = A  + (size_t)(by * BM) * K;
  const u16* Bb = Bm + (size_t)(bx * BN) * K;
  const int wave = tid >> 6, lane = tid & 63;
  const int wr = wave >> 1, wc = wave & 1;
  const int m0 = wr * (BM / 2), n0 = wc * (BN / 2);
  const int lm = lane & 15, qd = lane >> 4;

  if (EPI == 1) {
    // preload epilogue data up front (ready; in-loop barriers cover the sync)
    for (int e = tid; e < BM * 4; e += 256) {
      int r = e >> 2, q = e & 3;
      gate_s[e] = A2[(size_t)(by * BM + r) * KA2 + NJK + 128 + bx * 4 + q];
    }
    for (int e = tid; e < BN; e += 256)
      cv_s[e] = cvec[bx * BN + e] + cvec[4096 + bx * BN + e] + cvec[8192 + bx * BN + e];
  }

  f32x4 acc[WM][WN];
  const f32x4 zero = {0.f, 0.f, 0.f, 0.f};
  for (int mi = 0; mi < WM; ++mi)
    for (int ni = 0; ni < WN; ++ni) acc[mi][ni] = zero;

  for (int k0 = kbase; k0 < kbase + Kc; k0 += 64) {
#pragma unroll
    for (int i = 0; i < BM / 32; ++i) {
      int id = tid + 256 * i;
      int row = id >> 3, u = id & 7;
      gload16(Ab + (size_t)row * K + k0 + ((u ^ (row & 7)) * 8), &As[id * 8]);
    }
#pragma unroll
    for (int i = 0; i < BN / 32; ++i) {
      int id = tid + 256 * i;
      int row = id >> 3, u = id & 7;
      gload16(Bb + (size_t)row * K + k0 + ((u ^ (row & 7)) * 8), &Bs[id * 8]);
    }
    __syncthreads();
#pragma unroll
    for (int s = 0; s < 2; ++s) {
      const int swz = ((s << 2) + qd) ^ (lm & 7);
      bf16x8 af[WM], bfv[WN];
#pragma unroll
      for (int mi = 0; mi < WM; ++mi)
        af[mi] = *(const bf16x8*)&As[(m0 + mi * 16 + lm) * 64 + swz * 8];
#pragma unroll
      for (int ni = 0; ni < WN; ++ni)
        bfv[ni] = *(const bf16x8*)&Bs[(n0 + ni * 16 + lm) * 64 + swz * 8];
#pragma unroll
      for (int mi = 0; mi < WM; ++mi)
#pragma unroll
        for (int ni = 0; ni < WN; ++ni)
          acc[mi][ni] = __builtin_amdgcn_mfma_f32_16x16x32_bf16(af[mi], bfv[ni],
                                                                acc[mi][ni], 0, 0, 0);
    }
    __syncthreads();
  }

  const int rb = qd * 4;
#pragma unroll
  for (int mi = 0; mi < WM; ++mi) {
#pragma unroll
    for (int ni = 0; ni < WN; ++ni) {
#pragma unroll
      for (int r = 0; r < 4; ++r) {
        int ml = m0 + mi * 16 + rb + r;
        int nl = n0 + ni * 16 + lm;
        int gm = by * BM + ml;
        int gn = bx * BN + nl;
        float v = acc[mi][ni][r];
        if (EPI == 1) {
          v += cv_s[nl];
          v = v > 0.f ? v : 0.f;
          u16 gbit = gate_s[ml * 4 + (nl >> 5)];
          v = gbit ? v : 0.f;
          float vn = __shfl_xor(v, 1, 64);        // pack even/odd columns
          if ((lm & 1) == 0) {
            unsigned pk = (unsigned)f2bf(v) | ((unsigned)f2bf(vn) << 16);
            *(unsigned*)&A2[(size_t)gm * KA2 + gn] = pk;
          }
        } else {
          outF[((size_t)bz * B_SZ + gm) * DDATA + gn] = v;
        }
      }
    }
  }
}

// ---------------- reduce split-K partials + bias ----------------
__global__ __launch_bounds__(256) void k_reduce(const float* __restrict__ part,
                                                const float* __restrict__ bias,
                                                float* __restrict__ out) {
  const int N4 = B_SZ * DDATA / 4;
  int i = blockIdx.x * 256 + threadIdx.x;
  const float4* p4 = (const float4*)part;
  float4 s = p4[i];
#pragma unroll
  for (int z = 1; z < SPLITK; ++z) {
    float4 t = p4[i + z * N4];
    s.x += t.x; s.y += t.y; s.z += t.z; s.w += t.w;
  }
  float4 b = ((const float4*)bias)[i % (DDATA / 4)];
  s.x += b.x; s.y += b.y; s.z += b.z; s.w += b.w;
  ((float4*)out)[i] = s;
}

extern "C" void kernel_launch(void* const* d_in, const int* in_sizes, int n_in,
                              void* d_out, int out_size, void* d_ws, size_t ws_size,
                              hipStream_t stream) {
  const float* x   = (const float*)d_in[0];
  const float* We0 = (const float*)d_in[1];
  const float* be0 = (const float*)d_in[2];
  const float* Wd0 = (const float*)d_in[3];
  const float* bd0 = (const float*)d_in[4];
  const float* We1 = (const float*)d_in[5];
  const float* be1 = (const float*)d_in[6];
  const float* Wd1 = (const float*)d_in[7];
  const float* bd1 = (const float*)d_in[8];
  float* out = (float*)d_out;

  uint8_t* ws = (uint8_t*)d_ws;
  size_t off = 0;
  auto carve = [&](size_t bytes) {
    uint8_t* p = ws + off;
    off += (bytes + 255) & ~(size_t)255;
    return p;
  };
  u16*    A2   = (u16*)carve((size_t)B_SZ * KA2 * 2);
  u16*    xb   = (u16*)carve((size_t)B_SZ * DDATA * 2);
  u16*    W1T  = (u16*)carve((size_t)NJK * DDATA * 2);
  u16*    B2T  = (u16*)carve((size_t)DDATA * KA2 * 2);
  float*  cvp  = (float*)carve((size_t)3 * NJK * 4);
  float*  part = (float*)carve((size_t)SPLITK * B_SZ * DDATA * 4);   // 25.2 MB

  // all pre-GEMM work (gate+acts0+fixup, W1T/cv, B2T, x-cast) in one kernel
  k_front <<<1712, 256, 0, stream>>>(x, We0, be0, bd0, We1, bd1, be1, Wd1, Wd0,
                                     W1T, cvp, B2T, xb, A2);
  // GEMM1: acts1 -> A2[:, 0..4095]   (M=2048, N=4096, K=768), XCD-chunked
  k_gemm<128, 128, 1><<<512, 256, 0, stream>>>(xb, W1T, DDATA, DDATA,
                                               nullptr, A2, cvp);
  // GEMM2 split-K: part[z] = A2 @ B2 over K-chunk z   (M=2048, N=768, K=4352)
  // BM=64, SPLITK=4 -> 768 blocks (3/CU); staging 535->321MB, B-panels L2-local
  k_gemm<64, 128, 2><<<768, 256, 0, stream>>>(A2, B2T, KA2, KC2,
                                              part, nullptr, nullptr);
  k_reduce<<<1536, 256, 0, stream>>>(part, bd0, out);
}

// Round 3
// 153.195 us; speedup vs baseline: 1.2022x; 1.0552x over previous
//
#include <hip/hip_runtime.h>
#include <hip/hip_bf16.h>
#include <stdint.h>

#define B_SZ   2048
#define DDATA  768
#define NSAE   128
#define NJK    4096   // NSAE*32
#define KA2    4352   // NJK + 128 (acts0) + 128 (gate)
#define SPLITK 4
#define KC2    1088   // KA2 / SPLITK (17 x BK=64)

typedef unsigned short u16;
typedef short bf16x8 __attribute__((ext_vector_type(8)));
typedef float f32x4  __attribute__((ext_vector_type(4)));

static __device__ __forceinline__ u16 f2bf(float f) {
  __hip_bfloat16 h = __float2bfloat16(f);
  return *reinterpret_cast<u16*>(&h);
}

static __device__ __forceinline__ void gload16(const u16* g, u16* l) {
  __builtin_amdgcn_global_load_lds(
      (const __attribute__((address_space(1))) unsigned int*)g,
      (__attribute__((address_space(3))) unsigned int*)l,
      16, 0, 0);
}

// ======== k_front: ALL pre-GEMM work in ONE kernel ========
// blocks    0..511 : gate/acts0: 4 rows/block, 4 waves split d into 192-chunks
//                    (short exposed load chains, 10 indep FMA chains/load),
//                    LDS cross-wave reduce, fused x->bf16 cast, fp64 fix-up.
// blocks  512..895 : expert j transpose We1[j]->W1T, dbk seg-split 3x;
//                    cv partials to cvp[seg] (summed in GEMM1 preload)
// blocks 896..1711 : B2T build ([W_dec1 ; W_dec0 ; b_dec1]^T), 68 rb x 12 dbk
__global__ __launch_bounds__(256) void k_front(const float* __restrict__ x,
                                               const float* __restrict__ We0,
                                               const float* __restrict__ be0,
                                               const float* __restrict__ bd0,
                                               const float* __restrict__ We1,
                                               const float* __restrict__ bd1,
                                               const float* __restrict__ be1,
                                               const float* __restrict__ Wd1,
                                               const float* __restrict__ Wd0,
                                               u16* __restrict__ W1T,
                                               float* __restrict__ cvp,
                                               u16* __restrict__ B2T,
                                               u16* __restrict__ xb,
                                               u16* __restrict__ A2) {
  __shared__ float smem[6280];                  // 25.1 KB, shared by all branches
  const int bid = blockIdx.x, t = threadIdx.x;
  if (bid < 512) {
    // ---------------- gate branch: rows b0..b0+3 ----------------
    const int b0 = bid * 4;
    float* xs   = smem;                         // [4][768] = x - bd0
    float* part = smem + 3072;                  // [4 waves][4 rows][128]
    float* wqp  = smem + 5120;                  // [4 waves][128] ||We0||^2 partials
    float* xns  = smem + 5632;                  // [4] row norms
#pragma unroll
    for (int i = 0; i < 3; ++i) {
      int idx = t + i * 256;                    // 768 float4
      int r = idx / 192, c4 = idx % 192;
      size_t go = (size_t)(b0 + r) * DDATA + c4 * 4;
      float4 v = *(const float4*)&x[go];
      ushort4 o;
      o.x = f2bf(v.x); o.y = f2bf(v.y); o.z = f2bf(v.z); o.w = f2bf(v.w);
      *(ushort4*)&xb[go] = o;                   // fused x cast for GEMM1
      float4 b4 = *(const float4*)&bd0[c4 * 4];
      v.x -= b4.x; v.y -= b4.y; v.z -= b4.z; v.w -= b4.w;
      *(float4*)&xs[r * DDATA + c4 * 4] = v;
    }
    __syncthreads();
    const int ln = t & 63, w = t >> 6;
    {                                           // row norm: wave w owns row w
      float a = 0.f;
#pragma unroll
      for (int q = 0; q < 12; ++q) { float xv = xs[w * DDATA + ln + q * 64]; a += xv * xv; }
#pragma unroll
      for (int sh = 32; sh; sh >>= 1) a += __shfl_xor(a, sh, 64);
      if (ln == 0) xns[w] = a;
    }
    const int j0 = ln * 2;                      // 2 experts per lane
    // wave w accumulates d in [w*192, w*192+192) for ALL 4 rows (partials)
    float a00=0.f,a01=0.f,a10=0.f,a11=0.f,a20=0.f,a21=0.f,a30=0.f,a31=0.f;
    float wq0=0.f, wq1=0.f;
    const int dbase = w * 192;
    for (int d = dbase; d < dbase + 192; d += 4) {
      float4 xv0 = *(const float4*)&xs[0 * DDATA + d];   // wave-uniform bcast
      float4 xv1 = *(const float4*)&xs[1 * DDATA + d];
      float4 xv2 = *(const float4*)&xs[2 * DDATA + d];
      float4 xv3 = *(const float4*)&xs[3 * DDATA + d];
#pragma unroll
      for (int dd = 0; dd < 4; ++dd) {
        float2 w2 = *(const float2*)&We0[(size_t)(d + dd) * 128 + j0];
        float x0 = ((const float*)&xv0)[dd], x1 = ((const float*)&xv1)[dd];
        float x2 = ((const float*)&xv2)[dd], x3 = ((const float*)&xv3)[dd];
        a00 += x0 * w2.x; a01 += x0 * w2.y;
        a10 += x1 * w2.x; a11 += x1 * w2.y;
        a20 += x2 * w2.x; a21 += x2 * w2.y;
        a30 += x3 * w2.x; a31 += x3 * w2.y;
        wq0 += w2.x * w2.x; wq1 += w2.y * w2.y;
      }
    }
    *(float2*)&part[(w * 4 + 0) * 128 + j0] = make_float2(a00, a01);
    *(float2*)&part[(w * 4 + 1) * 128 + j0] = make_float2(a10, a11);
    *(float2*)&part[(w * 4 + 2) * 128 + j0] = make_float2(a20, a21);
    *(float2*)&part[(w * 4 + 3) * 128 + j0] = make_float2(a30, a31);
    *(float2*)&wqp[w * 128 + j0] = make_float2(wq0, wq1);
    __syncthreads();
    // finalize: wave w owns row w; lane handles experts j0, j0+1
    float p0 = be0[j0], p1 = be0[j0 + 1];
    float wn0 = 0.f, wn1 = 0.f;
#pragma unroll
    for (int q = 0; q < 4; ++q) {
      float2 pr = *(const float2*)&part[(q * 4 + w) * 128 + j0];
      p0 += pr.x; p1 += pr.y;
      float2 wr2 = *(const float2*)&wqp[q * 128 + j0];
      wn0 += wr2.x; wn1 += wr2.y;
    }
    const float sx = sqrtf(xns[w]);
    const float tau0 = 1e-4f * sx * sqrtf(wn0);
    const float tau1 = 1e-4f * sx * sqrtf(wn1);
    const int bb = b0 + w;
    const size_t row = (size_t)bb * KA2;
    unsigned pk = (unsigned)f2bf(p0 > 0.f ? p0 : 0.f) |
                  ((unsigned)f2bf(p1 > 0.f ? p1 : 0.f) << 16);
    unsigned gk = (p0 > 0.f ? 0x3F80u : 0u) | (p1 > 0.f ? 0x3F800000u : 0u);
    *(unsigned*)&A2[row + NJK + j0]       = pk;
    *(unsigned*)&A2[row + NJK + 128 + j0] = gk;
    // fp32 sign uncertain -> whole wave cooperates on exact fp64 recompute
#pragma unroll
    for (int c = 0; c < 2; ++c) {
      float pv = c ? p1 : p0;
      float tv = c ? tau1 : tau0;
      unsigned long long mask = __ballot(fabsf(pv) <= tv);
      while (mask) {
        int src = (int)__builtin_ctzll(mask);
        mask &= mask - 1;
        int jj = src * 2 + c;
        double acc = 0.0;
#pragma unroll
        for (int q = 0; q < 12; ++q) {
          int d = ln + q * 64;
          acc += (double)(x[(size_t)bb * DDATA + d] - bd0[d]) *
                 (double)We0[(size_t)d * 128 + jj];
        }
#pragma unroll
        for (int sh = 32; sh; sh >>= 1) acc += __shfl_xor(acc, sh, 64);
        if (ln == src) {
          double pd = acc + (double)be0[jj];
          A2[row + NJK + jj]       = f2bf(pd > 0.0 ? (float)pd : 0.f);
          A2[row + NJK + 128 + jj] = (pd > 0.0) ? (u16)0x3F80 : (u16)0;
        }
      }
    }
  } else if (bid < 896) {
    // ---------------- We1 transpose + cv partials (j, seg) ----------------
    const int e = bid - 512;
    const int j = e & 127, seg = e >> 7;        // seg 0..2 -> dbk seg*4..seg*4+3
    float* ts  = smem;                          // 64*33
    float* bds = smem + 64 * 33;                // 64
    float* red = smem + 64 * 33 + 64;           // 8*32
    const int k = t & 31, g = t >> 5;
    float cacc = 0.f;
    for (int db = seg * 4; db < seg * 4 + 4; ++db) {
      const float* src = We1 + (size_t)j * 24576 + db * 2048;  // 64 d x 32 k
#pragma unroll
      for (int i = 0; i < 8; ++i) {
        int ee = t + i * 256;
        ts[(ee >> 5) * 33 + (ee & 31)] = src[ee];
      }
      if (t < 64) bds[t] = bd1[(size_t)j * DDATA + db * 64 + t];
      __syncthreads();
#pragma unroll
      for (int i = 0; i < 8; ++i) {
        int ee = t + i * 256;
        int kk = ee >> 6, d = ee & 63;
        W1T[(size_t)(j * 32 + kk) * DDATA + db * 64 + d] = f2bf(ts[d * 33 + kk]);
      }
#pragma unroll
      for (int q = 0; q < 8; ++q) {
        int d = g + 8 * q;
        cacc += ts[d * 33 + k] * bds[d];
      }
      __syncthreads();
    }
    red[g * 32 + k] = cacc;
    __syncthreads();
    if (g == 0) {
      float s = 0.f;
#pragma unroll
      for (int q = 0; q < 8; ++q) s += red[q * 32 + k];
      cvp[seg * 4096 + j * 32 + k] = (seg == 0 ? be1[j * 32 + k] : 0.f) - s;
    }
  } else {
    // ---------------- B2T build ----------------
    const int e2 = bid - 896;
    const int rb = e2 / 12, dbk = e2 % 12;
    const float* src; int r0, base;
    if (rb < 64)      { src = Wd1; r0 = rb * 64;        base = 0;    }
    else if (rb < 66) { src = Wd0; r0 = (rb - 64) * 64; base = 4096; }
    else              { src = bd1; r0 = (rb - 66) * 64; base = 4224; }
    const int d0 = dbk * 64;
#pragma unroll
    for (int i = 0; i < 16; ++i) {
      int ee = t + i * 256;
      int ri = ee >> 6, di = ee & 63;
      smem[ri * 65 + di] = src[(size_t)(r0 + ri) * DDATA + d0 + di];
    }
    __syncthreads();
#pragma unroll
    for (int i = 0; i < 16; ++i) {
      int ee = t + i * 256;
      int di = ee >> 6, ri = ee & 63;
      B2T[(size_t)(d0 + di) * KA2 + base + r0 + ri] = f2bf(smem[ri * 65 + di]);
    }
  }
}

// ------ GEMM: C = A[M,K] * B^T[N,K], bf16 MFMA 16x16x32, BK=64, XOR-swizzled LDS ------
// T3-min + T4: double-buffered LDS, stage(t+1) issued BEFORE compute(t), raw
// s_barrier + COUNTED s_waitcnt vmcnt(LPS) so next-tile loads stay in flight
// across the barrier (never drain to 0 in the main loop).
// XCD-chunked 1-D grid: blocks sharing a B-panel land on ONE XCD (T1).
// EPI=1: v = relu(v + c[gn]) * gate -> bf16x2 A2 ;  EPI=2: split-K fp32 partials
template<int BM, int BN, int EPI>
__global__ __launch_bounds__(256) void k_gemm(const u16* __restrict__ A,
                                              const u16* __restrict__ Bm,
                                              int K, int Kc,
                                              float* __restrict__ outF,
                                              u16* __restrict__ A2,
                                              const float* __restrict__ cvec) {
  constexpr int WM = BM / 32, WN = BN / 32;
  constexpr int LPS = BM / 32 + BN / 32;        // gload16 per thread per stage
  __shared__ __align__(16) u16 As[2][BM * 64];
  __shared__ __align__(16) u16 Bs[2][BN * 64];
  __shared__ u16 gate_s[BM * 4];
  __shared__ float cv_s[BN];
  const int tid = threadIdx.x;
  int bx, by, bz;
  {
    const int h = blockIdx.x;
    if (EPI == 1) {
      const int l = (h & 7) * 64 + (h >> 3);    // bijective: 512 = 8*64
      const int g2 = l >> 6, w = l & 63;        // chunk g2 on XCD (h&7)
      by = w >> 2; bx = (g2 << 2) + (w & 3); bz = 0;
    } else {
      const int l = (h & 7) * 96 + (h >> 3);    // bijective: 768 = 8*96
      bx = l >> 7; const int r2 = l & 127; bz = r2 >> 5; by = r2 & 31;
    }
  }
  const int kbase = bz * Kc;
  const u16* Ab = A  + (size_t)(by * BM) * K;
  const u16* Bb = Bm + (size_t)(bx * BN) * K;
  const int wave = tid >> 6, lane = tid & 63;
  const int wr = wave >> 1, wc = wave & 1;
  const int m0 = wr * (BM / 2), n0 = wc * (BN / 2);
  const int lm = lane & 15, qd = lane >> 4;

  if (EPI == 1) {
    // preload epilogue data up front (each load consumed by its ds_write ->
    // vmcnt auto-drained before staging; in-loop barriers cover the sync)
    for (int e = tid; e < BM * 4; e += 256) {
      int r = e >> 2, q = e & 3;
      gate_s[e] = A2[(size_t)(by * BM + r) * KA2 + NJK + 128 + bx * 4 + q];
    }
    for (int e = tid; e < BN; e += 256)
      cv_s[e] = cvec[bx * BN + e] + cvec[4096 + bx * BN + e] + cvec[8192 + bx * BN + e];
  }

  f32x4 acc[WM][WN];
  const f32x4 zero = {0.f, 0.f, 0.f, 0.f};
  for (int mi = 0; mi < WM; ++mi)
    for (int ni = 0; ni < WN; ++ni) acc[mi][ni] = zero;

  auto stage = [&](int kt, int buf) {
    const int k0 = kbase + kt * 64;
#pragma unroll
    for (int i = 0; i < BM / 32; ++i) {
      int id = tid + 256 * i;
      int row = id >> 3, u = id & 7;
      gload16(Ab + (size_t)row * K + k0 + ((u ^ (row & 7)) * 8), &As[buf][id * 8]);
    }
#pragma unroll
    for (int i = 0; i < BN / 32; ++i) {
      int id = tid + 256 * i;
      int row = id >> 3, u = id & 7;
      gload16(Bb + (size_t)row * K + k0 + ((u ^ (row & 7)) * 8), &Bs[buf][id * 8]);
    }
  };

  const int NT = Kc / 64;
  stage(0, 0);                                  // prologue: fill buf0
  for (int t = 0; t < NT; ++t) {
    const int cur = t & 1;
    if (t + 1 < NT) {
      stage(t + 1, cur ^ 1);                    // issue next tile's loads
      // counted wait: drain stage(t)'s LPS loads, keep stage(t+1)'s in flight
      if constexpr (LPS == 8)      asm volatile("s_waitcnt vmcnt(8)" ::: "memory");
      else if constexpr (LPS == 6) asm volatile("s_waitcnt vmcnt(6)" ::: "memory");
      else                         asm volatile("s_waitcnt vmcnt(0)" ::: "memory");
    } else {
      asm volatile("s_waitcnt vmcnt(0)" ::: "memory");
    }
    __builtin_amdgcn_s_barrier();               // buf[cur] ready for all waves
#pragma unroll
    for (int s = 0; s < 2; ++s) {
      const int swz = ((s << 2) + qd) ^ (lm & 7);
      bf16x8 af[WM], bfv[WN];
#pragma unroll
      for (int mi = 0; mi < WM; ++mi)
        af[mi] = *(const bf16x8*)&As[cur][(m0 + mi * 16 + lm) * 64 + swz * 8];
#pragma unroll
      for (int ni = 0; ni < WN; ++ni)
        bfv[ni] = *(const bf16x8*)&Bs[cur][(n0 + ni * 16 + lm) * 64 + swz * 8];
#pragma unroll
      for (int mi = 0; mi < WM; ++mi)
#pragma unroll
        for (int ni = 0; ni < WN; ++ni)
          acc[mi][ni] = __builtin_amdgcn_mfma_f32_16x16x32_bf16(af[mi], bfv[ni],
                                                                acc[mi][ni], 0, 0, 0);
    }
    if (t + 1 < NT)
      __builtin_amdgcn_s_barrier();             // all reads of buf[cur] done ->
  }                                             // safe to overwrite at t+2

  const int rb = qd * 4;
#pragma unroll
  for (int mi = 0; mi < WM; ++mi) {
#pragma unroll
    for (int ni = 0; ni < WN; ++ni) {
#pragma unroll
      for (int r = 0; r < 4; ++r) {
        int ml = m0 + mi * 16 + rb + r;
        int nl = n0 + ni * 16 + lm;
        int gm = by * BM + ml;
        int gn = bx * BN + nl;
        float v = acc[mi][ni][r];
        if (EPI == 1) {
          v += cv_s[nl];
          v = v > 0.f ? v : 0.f;
          u16 gbit = gate_s[ml * 4 + (nl >> 5)];
          v = gbit ? v : 0.f;
          float vn = __shfl_xor(v, 1, 64);        // pack even/odd columns
          if ((lm & 1) == 0) {
            unsigned pk = (unsigned)f2bf(v) | ((unsigned)f2bf(vn) << 16);
            *(unsigned*)&A2[(size_t)gm * KA2 + gn] = pk;
          }
        } else {
          outF[((size_t)bz * B_SZ + gm) * DDATA + gn] = v;
        }
      }
    }
  }
}

// ---------------- reduce split-K partials + bias ----------------
__global__ __launch_bounds__(256) void k_reduce(const float* __restrict__ part,
                                                const float* __restrict__ bias,
                                                float* __restrict__ out) {
  const int N4 = B_SZ * DDATA / 4;
  int i = blockIdx.x * 256 + threadIdx.x;
  const float4* p4 = (const float4*)part;
  float4 s = p4[i];
#pragma unroll
  for (int z = 1; z < SPLITK; ++z) {
    float4 t = p4[i + z * N4];
    s.x += t.x; s.y += t.y; s.z += t.z; s.w += t.w;
  }
  float4 b = ((const float4*)bias)[i % (DDATA / 4)];
  s.x += b.x; s.y += b.y; s.z += b.z; s.w += b.w;
  ((float4*)out)[i] = s;
}

extern "C" void kernel_launch(void* const* d_in, const int* in_sizes, int n_in,
                              void* d_out, int out_size, void* d_ws, size_t ws_size,
                              hipStream_t stream) {
  const float* x   = (const float*)d_in[0];
  const float* We0 = (const float*)d_in[1];
  const float* be0 = (const float*)d_in[2];
  const float* Wd0 = (const float*)d_in[3];
  const float* bd0 = (const float*)d_in[4];
  const float* We1 = (const float*)d_in[5];
  const float* be1 = (const float*)d_in[6];
  const float* Wd1 = (const float*)d_in[7];
  const float* bd1 = (const float*)d_in[8];
  float* out = (float*)d_out;

  uint8_t* ws = (uint8_t*)d_ws;
  size_t off = 0;
  auto carve = [&](size_t bytes) {
    uint8_t* p = ws + off;
    off += (bytes + 255) & ~(size_t)255;
    return p;
  };
  u16*    A2   = (u16*)carve((size_t)B_SZ * KA2 * 2);
  u16*    xb   = (u16*)carve((size_t)B_SZ * DDATA * 2);
  u16*    W1T  = (u16*)carve((size_t)NJK * DDATA * 2);
  u16*    B2T  = (u16*)carve((size_t)DDATA * KA2 * 2);
  float*  cvp  = (float*)carve((size_t)3 * NJK * 4);
  float*  part = (float*)carve((size_t)SPLITK * B_SZ * DDATA * 4);   // 25.2 MB

  // all pre-GEMM work (gate+acts0+fixup, W1T/cv, B2T, x-cast) in one kernel
  k_front <<<1712, 256, 0, stream>>>(x, We0, be0, bd0, We1, bd1, be1, Wd1, Wd0,
                                     W1T, cvp, B2T, xb, A2);
  // GEMM1: acts1 -> A2[:, 0..4095]   (M=2048, N=4096, K=768), dbuf+counted vmcnt
  k_gemm<128, 128, 1><<<512, 256, 0, stream>>>(xb, W1T, DDATA, DDATA,
                                               nullptr, A2, cvp);
  // GEMM2 split-K: part[z] = A2 @ B2 over K-chunk z   (M=2048, N=768, K=4352)
  // BM=64, SPLITK=4 -> 768 blocks (3/CU), dbuf LDS 50KB -> 3/CU holds
  k_gemm<64, 128, 2><<<768, 256, 0, stream>>>(A2, B2T, KA2, KC2,
                                              part, nullptr, nullptr);
  k_reduce<<<1536, 256, 0, stream>>>(part, bd0, out);
}